// Round 7
// baseline (435.103 us; speedup 1.0000x reference)
//
#include <hip/hip_runtime.h>

#define D    512
#define HW   196   // 14*14
#define NS   8     // K-split count for the small GEMMs
#define MS   16    // k-split count for the KB passes
#define GRID 512   // 2 blocks/CU on 256 CUs; capacity is 4/CU via launch_bounds

// Workspace layout (floats):
//   p_part   [NS][128][512]   @ 0        (524288)
//   t12_part [NS][128][1024]  @ 524288   (1048576)
//   w_part   [NS][128][512]   @ 1572864  (524288)
//   beta     [128]            @ 2097152
//   mvp      [128][MS][196]   @ 2097280  (401408)
//   barrier  [2] uints        @ 2498688  (cnt, gen)

__global__ void k_init(unsigned* __restrict__ bar) {
    if (threadIdx.x < 2) bar[threadIdx.x] = 0u;
}

// Device-scope two-phase barrier: counter + generation. Last arriver resets
// cnt BEFORE releasing gen, so reuse across barriers/replays is safe.
__device__ __forceinline__ void grid_barrier(unsigned* bar) {
    __threadfence();              // flush this thread's writes to device scope
    __syncthreads();
    if (threadIdx.x == 0) {
        unsigned* cnt = bar;
        unsigned* gen = bar + 1;
        unsigned g = __hip_atomic_load(gen, __ATOMIC_RELAXED, __HIP_MEMORY_SCOPE_AGENT);
        unsigned a = __hip_atomic_fetch_add(cnt, 1u, __ATOMIC_ACQ_REL, __HIP_MEMORY_SCOPE_AGENT);
        if (a == GRID - 1) {
            __hip_atomic_store(cnt, 0u, __ATOMIC_RELAXED, __HIP_MEMORY_SCOPE_AGENT);
            __hip_atomic_fetch_add(gen, 1u, __ATOMIC_RELEASE, __HIP_MEMORY_SCOPE_AGENT);
        } else {
            while (__hip_atomic_load(gen, __ATOMIC_ACQUIRE, __HIP_MEMORY_SCOPE_AGENT) == g)
                __builtin_amdgcn_s_sleep(8);
        }
    }
    __syncthreads();
}

__global__ __launch_bounds__(256, 4)
void k_all(const float* __restrict__ m_prev, const float* __restrict__ KB,
           const float* __restrict__ c,      const float* __restrict__ W_m,
           const float* __restrict__ b_m,    const float* __restrict__ W_kb,
           const float* __restrict__ b_kb,   const float* __restrict__ W_merge,
           const float* __restrict__ b_merge,const float* __restrict__ W_attn,
           const float* __restrict__ b_attn,
           float* __restrict__ p_part, float* __restrict__ t12_part,
           float* __restrict__ w_part, float* __restrict__ beta_g,
           float* __restrict__ mvp,    float* __restrict__ out,
           unsigned* __restrict__ bar) {
    const int bid = blockIdx.x;
    const int t   = threadIdx.x;

    __shared__ float  xs[16][64];
    __shared__ float  red[4];
    __shared__ float  wl[32];
    __shared__ float4 mv4_s[49];

    // ================= Phase A: p partials (0..127), t12 partials (128..383)
    if (bid < 128) {                      // ---- p: (jt2, bt8, kt8) ----
        const int jt = bid & 1, bt = (bid >> 1) & 7, kt = bid >> 4;
        const int j  = jt * 256 + t;
        const int b0 = bt * 16;
        const int k0 = kt * 64;
        for (int i = t; i < 16 * 64; i += 256)
            xs[i >> 6][i & 63] = m_prev[(b0 + (i >> 6)) * D + k0 + (i & 63)];
        __syncthreads();
        float acc[16];
        #pragma unroll
        for (int bb = 0; bb < 16; ++bb) acc[bb] = 0.f;
        for (int kk = 0; kk < 64; ++kk) {
            float wv = W_m[(k0 + kk) * D + j];        // coalesced across lanes
            #pragma unroll
            for (int bb = 0; bb < 16; ++bb) acc[bb] += xs[bb][kk] * wv;
        }
        const float bias = (kt == 0) ? b_m[j] : 0.f;  // bias folded into split 0
        #pragma unroll
        for (int bb = 0; bb < 16; ++bb)
            p_part[((size_t)kt * 128 + b0 + bb) * D + j] = acc[bb] + bias;
    } else if (bid < 384) {               // ---- t12: (kkt4, bt8, jt8) ----
        const int i2 = bid - 128;
        const int kkt = i2 & 3, bt = (i2 >> 2) & 7, jt = i2 >> 5;
        const int kk = kkt * 256 + t;     // 0..1023
        const int b0 = bt * 16;
        const int j0 = jt * 64;
        for (int i = t; i < 16 * 64; i += 256) {
            int bb = i >> 6, jj = i & 63;
            xs[bb][jj] = c[(b0 + bb) * D + j0 + jj] * W_attn[j0 + jj];
        }
        __syncthreads();
        float acc[16];
        #pragma unroll
        for (int bb = 0; bb < 16; ++bb) acc[bb] = 0.f;
        const float4* wrow = (const float4*)&W_merge[(size_t)kk * D + j0];
        for (int q = 0; q < 16; ++q) {
            float4 w4 = wrow[q];
            #pragma unroll
            for (int bb = 0; bb < 16; ++bb)
                acc[bb] += xs[bb][4*q+0] * w4.x + xs[bb][4*q+1] * w4.y
                         + xs[bb][4*q+2] * w4.z + xs[bb][4*q+3] * w4.w;
        }
        #pragma unroll
        for (int bb = 0; bb < 16; ++bb)
            t12_part[((size_t)jt * 128 + b0 + bb) * 1024 + kk] = acc[bb];
    }
    grid_barrier(bar);

    // ================= Phase B: w partials (0..127), beta (128..255)
    if (bid < 128) {                      // ---- w: (kpt2, bt8, kt8) ----
        const int kpt = bid & 1, bt = (bid >> 1) & 7, kt = bid >> 4;
        const int kp = kpt * 256 + t;
        const int b0 = bt * 16;
        const int k0 = kt * 64;
        for (int i = t; i < 16 * 64; i += 256) {
            int bb = i >> 6, kk = i & 63;
            int b = b0 + bb, k = k0 + kk;
            float pv = 0.f, tv = 0.f;
            #pragma unroll
            for (int s = 0; s < NS; ++s) {
                pv += p_part[((size_t)s * 128 + b) * D + k];
                tv += t12_part[((size_t)s * 128 + b) * 1024 + k];   // t1 = cols [0,512)
            }
            xs[bb][kk] = pv * tv;
        }
        __syncthreads();
        float acc[16];
        #pragma unroll
        for (int bb = 0; bb < 16; ++bb) acc[bb] = 0.f;
        const float4* wrow = (const float4*)&W_kb[(size_t)kp * D + k0];
        for (int q = 0; q < 16; ++q) {
            float4 w4 = wrow[q];
            #pragma unroll
            for (int bb = 0; bb < 16; ++bb)
                acc[bb] += xs[bb][4*q+0] * w4.x + xs[bb][4*q+1] * w4.y
                         + xs[bb][4*q+2] * w4.z + xs[bb][4*q+3] * w4.w;
        }
        #pragma unroll
        for (int bb = 0; bb < 16; ++bb) {
            float extra = 0.f;
            if (kt == 0) {                // fold t2 into split 0
                #pragma unroll
                for (int s = 0; s < NS; ++s)
                    extra += t12_part[((size_t)s * 128 + b0 + bb) * 1024 + 512 + kp];
            }
            w_part[((size_t)kt * 128 + b0 + bb) * D + kp] = acc[bb] + extra;
        }
    } else if (bid < 256) {               // ---- beta ----
        const int b = bid - 128;
        float sum = 0.f;
        for (int j = t; j < D; j += 256) {
            float pv = 0.f, tv = 0.f;
            #pragma unroll
            for (int s = 0; s < NS; ++s) {
                pv += p_part[((size_t)s * 128 + b) * D + j];
                tv += t12_part[((size_t)s * 128 + b) * 1024 + j];
            }
            float u = c[b * D + j] * W_attn[j];
            sum += b_merge[j] * u + b_kb[j] * (pv * tv);
        }
        #pragma unroll
        for (int off = 32; off; off >>= 1) sum += __shfl_down(sum, off, 64);
        if ((t & 63) == 0) red[t >> 6] = sum;
        __syncthreads();
        if (t == 0) beta_g[b] = red[0] + red[1] + red[2] + red[3] + b_attn[0];
    }
    grid_barrier(bar);

    // ================= Phase C: mvp (2048 items, grid-stride x4)
    for (int it = bid; it < 128 * MS; it += GRID) {
        const int b  = it >> 4;
        const int ks = it & (MS - 1);
        __syncthreads();                  // protect wl from previous iteration
        if (t < 32) {
            float s = 0.f;
            #pragma unroll
            for (int q = 0; q < NS; ++q)
                s += w_part[((size_t)q * 128 + b) * D + ks * 32 + t];
            wl[t] = s;
        }
        __syncthreads();
        if (t < HW) {
            const float* kbp = KB + (size_t)b * D * HW + (size_t)ks * 32 * HW + t;
            float acc = 0.f;
            #pragma unroll
            for (int k = 0; k < 32; ++k) acc += kbp[(size_t)k * HW] * wl[k];
            mvp[((size_t)b * MS + ks) * HW + t] = acc;
        }
    }
    grid_barrier(bar);

    // ================= Phase D: out (2048 items, grid-stride x4)
    for (int it = bid; it < 128 * 16; it += GRID) {
        const int b  = it >> 4;
        const int kt = it & 15;
        const int wave = t >> 6, lane = t & 63;
        __syncthreads();                  // protect mv4_s from previous iteration
        if (t < HW) {
            float s = beta_g[b];
            #pragma unroll
            for (int q = 0; q < MS; ++q)
                s += mvp[((size_t)b * MS + q) * HW + t];
            ((float*)mv4_s)[t] = s;
        }
        __syncthreads();
        const float4 m4 = (lane < 49) ? mv4_s[lane] : make_float4(0.f, 0.f, 0.f, 0.f);
        #pragma unroll
        for (int i = 0; i < 8; ++i) {
            const int k = kt * 32 + wave * 8 + i;
            float p = 0.f;
            if (lane < 49) {
                float4 v = ((const float4*)(KB + ((size_t)b * D + k) * HW))[lane];
                p = v.x * m4.x + v.y * m4.y + v.z * m4.z + v.w * m4.w;
            }
            #pragma unroll
            for (int off = 32; off; off >>= 1) p += __shfl_xor(p, off, 64);
            if (lane == 0) out[(size_t)b * D + k] = p;
        }
    }
}

// ---------------------------------------------------------------------------
extern "C" void kernel_launch(void* const* d_in, const int* in_sizes, int n_in,
                              void* d_out, int out_size, void* d_ws, size_t ws_size,
                              hipStream_t stream) {
    const float* m_prev  = (const float*)d_in[0];
    const float* KB      = (const float*)d_in[1];
    const float* c_i     = (const float*)d_in[2];
    const float* W_m     = (const float*)d_in[3];
    const float* b_m     = (const float*)d_in[4];
    const float* W_kb    = (const float*)d_in[5];
    const float* b_kb    = (const float*)d_in[6];
    const float* W_merge = (const float*)d_in[7];
    const float* b_merge = (const float*)d_in[8];
    const float* W_attn  = (const float*)d_in[9];
    const float* b_attn  = (const float*)d_in[10];
    float* out = (float*)d_out;

    float* ws       = (float*)d_ws;
    float* p_part   = ws;               // [NS][128][512]
    float* t12_part = ws + 524288;      // [NS][128][1024]
    float* w_part   = ws + 1572864;     // [NS][128][512]
    float* beta     = ws + 2097152;     // [128]
    float* mvp      = ws + 2097280;     // [128][MS][196]
    unsigned* bar   = (unsigned*)(ws + 2498688);   // [2]: cnt, gen

    k_init<<<1, 64, 0, stream>>>(bar);
    k_all <<<GRID, 256, 0, stream>>>(m_prev, KB, c_i, W_m, b_m, W_kb, b_kb,
                                     W_merge, b_merge, W_attn, b_attn,
                                     p_part, t12_part, w_part, beta, mvp, out, bar);
}

// Round 8
// 46.056 us; speedup vs baseline: 9.4473x; 9.4473x over previous
//
#include <hip/hip_runtime.h>

#define D   512
#define HW  196   // 14*14
#define NS  8     // K-split count for the small GEMMs
#define MS  16    // k-split count for the KB passes

// Workspace layout (floats):
//   p_part   [NS][128][512]   @ 0        (524288)
//   t12_part [NS][128][1024]  @ 524288   (1048576)
//   mvp      [128][MS][196]   @ 1572864  (401408)

// ---------------------------------------------------------------------------
// K1 (384 blocks): blocks 0..127 -> p partials, 128..383 -> t12 partials.
// (R5-proven structure, unchanged.)
// ---------------------------------------------------------------------------
__global__ void k_stage1(const float* __restrict__ m_prev, const float* __restrict__ W_m,
                         const float* __restrict__ b_m, const float* __restrict__ c,
                         const float* __restrict__ W_attn, const float* __restrict__ W_merge,
                         float* __restrict__ p_part, float* __restrict__ t12_part) {
    const int bx = blockIdx.x;
    const int t  = threadIdx.x;
    __shared__ float xs[16][64];

    if (bx < 128) {                       // ---- p: (jt2, bt8, kt8) ----
        const int jt = bx & 1, bt = (bx >> 1) & 7, kt = bx >> 4;
        const int j  = jt * 256 + t;
        const int b0 = bt * 16;
        const int k0 = kt * 64;
        for (int i = t; i < 16 * 64; i += 256)
            xs[i >> 6][i & 63] = m_prev[(b0 + (i >> 6)) * D + k0 + (i & 63)];
        __syncthreads();
        float acc[16];
        #pragma unroll
        for (int bb = 0; bb < 16; ++bb) acc[bb] = 0.f;
        for (int kk = 0; kk < 64; ++kk) {
            float wv = W_m[(k0 + kk) * D + j];        // coalesced across lanes
            #pragma unroll
            for (int bb = 0; bb < 16; ++bb) acc[bb] += xs[bb][kk] * wv;
        }
        const float bias = (kt == 0) ? b_m[j] : 0.f;  // bias folded into split 0
        #pragma unroll
        for (int bb = 0; bb < 16; ++bb)
            p_part[((size_t)kt * 128 + b0 + bb) * D + j] = acc[bb] + bias;
    } else {                              // ---- t12: (kkt4, bt8, jt8) ----
        const int i2 = bx - 128;
        const int kkt = i2 & 3, bt = (i2 >> 2) & 7, jt = i2 >> 5;
        const int kk = kkt * 256 + t;     // 0..1023
        const int b0 = bt * 16;
        const int j0 = jt * 64;
        for (int i = t; i < 16 * 64; i += 256) {
            int bb = i >> 6, jj = i & 63;
            xs[bb][jj] = c[(b0 + bb) * D + j0 + jj] * W_attn[j0 + jj];
        }
        __syncthreads();
        float acc[16];
        #pragma unroll
        for (int bb = 0; bb < 16; ++bb) acc[bb] = 0.f;
        const float4* wrow = (const float4*)&W_merge[(size_t)kk * D + j0];
        for (int q = 0; q < 16; ++q) {
            float4 w4 = wrow[q];
            #pragma unroll
            for (int bb = 0; bb < 16; ++bb)
                acc[bb] += xs[bb][4*q+0] * w4.x + xs[bb][4*q+1] * w4.y
                         + xs[bb][4*q+2] * w4.z + xs[bb][4*q+3] * w4.w;
        }
        #pragma unroll
        for (int bb = 0; bb < 16; ++bb)
            t12_part[((size_t)jt * 128 + b0 + bb) * 1024 + kk] = acc[bb];
    }
}

// ---------------------------------------------------------------------------
// K2 (2048 blocks (b, ks), 256 threads): fused w-chunk + beta + mv.
//   step1: fold r[b,:] = (Σs p_part)(Σs t1_part) into LDS; fold t2 chunk.
//   step2: w[32] = r · W_kb[ks rows]ᵀ + t2   (wave-per-row, coalesced,
//          r-fragment in registers, 64-lane shfl reduce)
//   beta (ks==0 only): Σ b_merge·u + b_kb·r + b_attn, folded into mvp[b][0].
//   step3: mvp[b][ks][hw] = Σ_{k in chunk} KB[b,k,hw]·w[k] (+beta)
// ---------------------------------------------------------------------------
__global__ __launch_bounds__(256, 4)
void k_wmv(const float* __restrict__ KB, const float* __restrict__ p_part,
           const float* __restrict__ t12_part, const float* __restrict__ W_kb,
           const float* __restrict__ c, const float* __restrict__ W_attn,
           const float* __restrict__ b_merge, const float* __restrict__ b_kb,
           const float* __restrict__ b_attn, float* __restrict__ mvp) {
    const int b    = blockIdx.x >> 4;
    const int ks   = blockIdx.x & (MS - 1);
    const int t    = threadIdx.x;
    const int wave = t >> 6, lane = t & 63;

    __shared__ float r_s[512];
    __shared__ float wl[32];
    __shared__ float winit[32];
    __shared__ float redB[4];

    // ---- step 1: fold r and t2-chunk (coalesced) ----
    for (int k = t; k < 512; k += 256) {
        float pv = 0.f, tv = 0.f;
        #pragma unroll
        for (int s = 0; s < NS; ++s) {
            pv += p_part[((size_t)s * 128 + b) * D + k];
            tv += t12_part[((size_t)s * 128 + b) * 1024 + k];   // t1 = cols [0,512)
        }
        r_s[k] = pv * tv;
    }
    if (t < 32) {
        float s2 = 0.f;
        #pragma unroll
        for (int s = 0; s < NS; ++s)
            s2 += t12_part[((size_t)s * 128 + b) * 1024 + 512 + ks * 32 + t];
        winit[t] = s2;
    }
    __syncthreads();

    // ---- beta (ks==0 blocks only) ----
    if (ks == 0) {
        float bsum = 0.f;
        for (int k = t; k < 512; k += 256)
            bsum += b_merge[k] * c[(size_t)b * D + k] * W_attn[k] + b_kb[k] * r_s[k];
        #pragma unroll
        for (int off = 32; off; off >>= 1) bsum += __shfl_down(bsum, off, 64);
        if (lane == 0) redB[wave] = bsum;
    }

    // ---- step 2: w rows (wave-per-row; r-fragment hoisted to registers) ----
    const float4 ra = *(const float4*)&r_s[lane * 8];
    const float4 rb = *(const float4*)&r_s[lane * 8 + 4];
    #pragma unroll
    for (int i = 0; i < 8; ++i) {
        const int row = ks * 32 + wave * 8 + i;
        const float4* wr = (const float4*)&W_kb[(size_t)row * D + lane * 8];
        float4 w0 = wr[0], w1 = wr[1];
        float dot = w0.x * ra.x + w0.y * ra.y + w0.z * ra.z + w0.w * ra.w
                  + w1.x * rb.x + w1.y * rb.y + w1.z * rb.z + w1.w * rb.w;
        #pragma unroll
        for (int off = 32; off; off >>= 1) dot += __shfl_down(dot, off, 64);
        if (lane == 0) wl[wave * 8 + i] = dot + winit[wave * 8 + i];
    }
    __syncthreads();

    // ---- step 3: mv chunk (R5-proven coalesced hw-lane pattern) ----
    float beta = 0.f;
    if (ks == 0) beta = redB[0] + redB[1] + redB[2] + redB[3] + b_attn[0];
    if (t < HW) {
        const float* kbp = KB + (size_t)b * D * HW + (size_t)ks * 32 * HW + t;
        float acc = beta;
        #pragma unroll
        for (int k = 0; k < 32; ++k) acc += kbp[(size_t)k * HW] * wl[k];
        mvp[((size_t)b * MS + ks) * HW + t] = acc;
    }
}

// ---------------------------------------------------------------------------
// K3 (2048 blocks (b, kt), 256 threads = 4 waves x 8 rows): out pass.
// mvp partials (beta already included) folded to LDS; one wave per (b,k) row,
// 49 lanes load the contiguous 784B row as float4, dot, butterfly-reduce.
// ---------------------------------------------------------------------------
__global__ void k_mnew(const float* __restrict__ KB, const float* __restrict__ mvp,
                       float* __restrict__ out) {
    const int b  = blockIdx.x >> 4;
    const int kt = blockIdx.x & 15;
    const int t  = threadIdx.x;
    const int wave = t >> 6, lane = t & 63;
    __shared__ float4 mv4_s[49];

    if (t < HW) {
        float s = 0.f;
        #pragma unroll
        for (int q = 0; q < MS; ++q)
            s += mvp[((size_t)b * MS + q) * HW + t];
        ((float*)mv4_s)[t] = s;
    }
    __syncthreads();

    const float4 m4 = (lane < 49) ? mv4_s[lane] : make_float4(0.f, 0.f, 0.f, 0.f);
    #pragma unroll
    for (int i = 0; i < 8; ++i) {
        const int k = kt * 32 + wave * 8 + i;
        float p = 0.f;
        if (lane < 49) {
            float4 v = ((const float4*)(KB + ((size_t)b * D + k) * HW))[lane];
            p = v.x * m4.x + v.y * m4.y + v.z * m4.z + v.w * m4.w;
        }
        #pragma unroll
        for (int off = 32; off; off >>= 1) p += __shfl_xor(p, off, 64);
        if (lane == 0) out[(size_t)b * D + k] = p;
    }
}

// ---------------------------------------------------------------------------
extern "C" void kernel_launch(void* const* d_in, const int* in_sizes, int n_in,
                              void* d_out, int out_size, void* d_ws, size_t ws_size,
                              hipStream_t stream) {
    const float* m_prev  = (const float*)d_in[0];
    const float* KB      = (const float*)d_in[1];
    const float* c_i     = (const float*)d_in[2];
    const float* W_m     = (const float*)d_in[3];
    const float* b_m     = (const float*)d_in[4];
    const float* W_kb    = (const float*)d_in[5];
    const float* b_kb    = (const float*)d_in[6];
    const float* W_merge = (const float*)d_in[7];
    const float* b_merge = (const float*)d_in[8];
    const float* W_attn  = (const float*)d_in[9];
    const float* b_attn  = (const float*)d_in[10];
    float* out = (float*)d_out;

    float* ws       = (float*)d_ws;
    float* p_part   = ws;               // [NS][128][512]
    float* t12_part = ws + 524288;      // [NS][128][1024]
    float* mvp      = ws + 1572864;     // [128][MS][196]

    k_stage1<<<384, 256, 0, stream>>>(m_prev, W_m, b_m, c_i, W_attn, W_merge,
                                      p_part, t12_part);
    k_wmv  <<<2048, 256, 0, stream>>>(KB, p_part, t12_part, W_kb, c_i, W_attn,
                                      b_merge, b_kb, b_attn, mvp);
    k_mnew <<<2048, 256, 0, stream>>>(KB, mvp, out);
}